// Round 19
// baseline (281.845 us; speedup 1.0000x reference)
//
#include <hip/hip_runtime.h>
#include <math.h>

// S4D — round 25: r24 (full-line direct IO, 16-h blocks) with L SEGMENTED
// into two halves of 32 chunks -> per-wave tile [32][72]+pad = 4640 B,
// 16 tiles = 74.2 KB -> TWO blocks/CU (r24: 147.9 KB -> 1 block/CU, so the
// stage->compute->store phases had nothing to overlap with; measured 49-55us
// vs ~34us IO + ~14us compute serial sum). Block A's staging now overlaps
// block B's compute. u carried in registers across segments; total MFMA/IO
// work unchanged; T/M rows stream from G twice (L2-resident).
// __launch_bounds__(1024,8) pins VGPR<=64 (r24 used exactly 64; the
// segment split halves xbA/xbB so pressure is lower).

#define H_  512
#define L_  4096
#define B_  8
#define N2_ 32
#define NC  64            // total chunks of 64 timesteps
#define SEG 32            // chunks per segment
#define RSTR 72           // tile inner row stride, f16 units (144 B)
#define TSTR 2320         // f16 per tile slot: 32*72 + 16 pad (4640 B)

typedef _Float16 f16;
typedef _Float16 f16x8 __attribute__((ext_vector_type(8)));
typedef _Float16 f16x4 __attribute__((ext_vector_type(4)));
typedef _Float16 f16x2 __attribute__((ext_vector_type(2)));
typedef float    f32x4 __attribute__((ext_vector_type(4)));

__device__ __forceinline__ float bfly1(float v) {   // xor 1: quad_perm [1,0,3,2]
    return __int_as_float(__builtin_amdgcn_update_dpp(
        0, __float_as_int(v), 0xB1, 0xf, 0xf, true));
}

// ---------------- kernel D: per-h matrix build (r22-r24, verified) ---------
// G[h][192][64] f16: T'(+D diag) rows 0..63, M 64..127, V 128..191.
// Lg[h][64] f32: Λ re [0:32), im [32:64).
__global__ __launch_bounds__(256) void k_build(
    const float* __restrict__ log_dt,
    const float* __restrict__ A_real_log,
    const float* __restrict__ A_imag,
    const float* __restrict__ B_re,
    const float* __restrict__ B_im,
    const float* __restrict__ C_re,
    const float* __restrict__ C_im,
    const float* __restrict__ Dv,
    f16*  __restrict__ G,
    float* __restrict__ Lg)
{
    __shared__ float pr[32 * 66], pi[32 * 66];     // dApow [n][66], p=0..64
    __shared__ float s_xr[32], s_xi[32], s_dBr[32], s_dBi[32],
                     s_wr[32], s_wi[32], s_wdr[32], s_wdi[32], s_k[64];
    const int h   = (int)blockIdx.x;
    const int tid = threadIdx.x;

    if (tid < 32) {
        const int n = tid, hn = h * N2_ + n;
        const float dt = expf(log_dt[h]);
        const float Ar = -expf(A_real_log[hn]);
        const float Ai = A_imag[hn];
        const float xr = dt * Ar, xi = dt * Ai;
        s_xr[n] = xr; s_xi[n] = xi;
        const float ex = expf(xr), cs = cosf(xi), sn = sinf(xi);
        const float sh  = sinf(0.5f * xi);
        const float emr = expm1f(xr) * cs - 2.0f * sh * sh;  // Re(expm1(dtA))
        const float emi = ex * sn;
        const float ia  = 1.0f / (Ar * Ar + Ai * Ai);
        const float tr  = (emr * Ar + emi * Ai) * ia;
        const float ti  = (emi * Ar - emr * Ai) * ia;
        const float Brv = B_re[hn], Biv = B_im[hn];
        const float dBr = Brv * tr - Biv * ti, dBi = Brv * ti + Biv * tr;
        s_dBr[n] = dBr; s_dBi[n] = dBi;
        const float wr = 2.0f * C_re[hn], wi = 2.0f * C_im[hn];
        s_wr[n] = wr; s_wi[n] = wi;
        s_wdr[n] = wr * dBr - wi * dBi;             // w*dB
        s_wdi[n] = wr * dBi + wi * dBr;
    }
    __syncthreads();

    for (int e = tid; e < 2048; e += 256) {         // p = 0..63
        const int n = e >> 6, p = e & 63;
        const float ex = expf((float)p * s_xr[n]);
        float sn, cs; sincosf((float)p * s_xi[n], &sn, &cs);
        pr[n * 66 + p] = ex * cs; pi[n * 66 + p] = ex * sn;
    }
    if (tid < 32) {                                 // p = 64
        const int n = tid;
        const float ex = expf(64.f * s_xr[n]);
        float sn, cs; sincosf(64.f * s_xi[n], &sn, &cs);
        pr[n * 66 + 64] = ex * cs; pi[n * 66 + 64] = ex * sn;
    }
    __syncthreads();

    if (tid < 64) {                                 // k[d] = Re(w dB dA^d)
        float acc = 0.f;
        for (int n = 0; n < 32; ++n)
            acc += s_wdr[n] * pr[n * 66 + tid] - s_wdi[n] * pi[n * 66 + tid];
        s_k[tid] = acc;
    }
    if (tid < 32) {                                 // Λ = dA^64
        Lg[h * 64 + tid]      = pr[tid * 66 + 64];
        Lg[h * 64 + 32 + tid] = pi[tid * 66 + 64];
    }
    const float Dh = Dv[h];
    f16* Gh = G + (size_t)h * 192 * 64;
    for (int e = tid; e < 4096; e += 256) {         // M rows 64..127
        const int t = e >> 6, j = e & 63, n = j >> 1;
        const float re = pr[n * 66 + t + 1], im = pi[n * 66 + t + 1];
        const float mv = (j & 1) ? -(s_wr[n] * im + s_wi[n] * re)
                                 :  (s_wr[n] * re - s_wi[n] * im);
        Gh[(size_t)(64 + t) * 64 + j] = (f16)mv;
    }
    for (int e = tid; e < 4096; e += 256) {         // V rows 128..191
        const int r = e >> 6, s = e & 63, n = r >> 1;
        const float re = pr[n * 66 + 63 - s], im = pi[n * 66 + 63 - s];
        const float vv = (r & 1) ? (s_dBr[n] * im + s_dBi[n] * re)
                                 : (s_dBr[n] * re - s_dBi[n] * im);
        Gh[(size_t)(128 + r) * 64 + s] = (f16)vv;
    }
    __syncthreads();                                // s_k ready for all
    for (int e = tid; e < 4096; e += 256) {         // T' rows 0..63 (+D diag)
        const int t = e >> 6, s = e & 63;
        const float tv = (s <= t) ? (s_k[t - s] + (s == t ? Dh : 0.f)) : 0.f;
        Gh[(size_t)t * 64 + s] = (f16)tv;
    }
}

// ---------------- kernel B: segmented full-line direct-IO convolution ------
__global__ __launch_bounds__(1024, 8) void s4d_conv_kernel(
    const float* __restrict__ x,          // (B, L, H) f32
    const f16*  __restrict__ G,           // (H, 192, 64) f16: T'/M/V
    const float* __restrict__ Lg,         // (H, 64) f32: Λ re|im
    float* __restrict__ y,                // (B, L, H) f32 (gelu'd)
    float* __restrict__ st_re,            // (B, H, N2)
    float* __restrict__ st_im)            // (B, H, N2)
{
    __shared__ f16 XT[16 * TSTR];                  // 74,240 B: 16 wave tiles

    // XCD swizzle: XCD k owns h-groups [4k,4k+4), all b.
    const int bid = (int)blockIdx.x;               // 0..255
    const int lb  = (bid & 7) * 32 + (bid >> 3);
    const int hg  = lb >> 3;                       // 0..31 (16-h group)
    const int b   = lb & 7;

    const int tid = threadIdx.x;
    const int l   = tid & 63;
    const int w   = tid >> 6;                      // wave -> h = hg*16 + w
    const int h   = hg * 16 + w;
    const int row16 = l & 15, kg = l >> 4;

    const f16* Gh = G + (size_t)h * 192 * 64;

    // ---- Vf preload (global, L2-resident) + Λ ----
    f16x8 Vf[4][2];
#pragma unroll
    for (int mt = 0; mt < 4; ++mt)
#pragma unroll
        for (int ks = 0; ks < 2; ++ks)
            Vf[mt][ks] = *(const f16x8*)
                &Gh[(size_t)(128 + mt * 16 + row16) * 64 + ks * 32 + kg * 8];
    const float lr  = Lg[h * 64 + (l >> 1)];
    const float li0 = Lg[h * 64 + 32 + (l >> 1)];
    const float lis = (l & 1) ? li0 : -li0;

    const int hq = tid & 3;                        // staging: h sub-quad
    const int tp = tid >> 2;                       // t-pair index 0..255
    const float* xb_ = x + (size_t)b * L_ * H_ + hg * 16 + hq * 4;
    float*       yb_ = y + (size_t)b * L_ * H_ + hg * 16 + hq * 4;
    f16* Xw = &XT[(((w & 3) << 2) | (w >> 2)) * TSTR];   // PHYS(w)

    float u = 0.f;                                 // recurrence state (j = l)

    for (int s = 0; s < 2; ++s) {
        const int tbase = s * (SEG * 64);          // 0 or 2048

        // ---- cooperative X staging: lane-quad = one FULL 64B line ----
#pragma unroll
        for (int iter = 0; iter < 4; ++iter) {
            const int t0 = tbase + iter * 512 + tp * 2;
            const f32x4 v0 = *(const f32x4*)&xb_[(size_t)t0 * H_];
            const f32x4 v1 = *(const f32x4*)&xb_[(size_t)(t0 + 1) * H_];
            const int c = (t0 >> 6) & (SEG - 1), s0 = t0 & 63;
#pragma unroll
            for (int j = 0; j < 4; ++j) {          // h_local = hq*4+j
                f16x2 p; p[0] = (f16)v0[j]; p[1] = (f16)v1[j];
                *(f16x2*)&XT[((j << 2) | hq) * TSTR + c * RSTR + s0] = p;
            }
        }
        __syncthreads();                           // X staged

        // ---- P5: P = V @ X; X fragments stay live for P7 ----
        f16x8 xbA[2], xbB[2];
#pragma unroll
        for (int nt = 0; nt < 2; ++nt) {
            const int col = nt * 16 + row16;
            xbA[nt] = *(const f16x8*)&Xw[col * RSTR + kg * 8];
            xbB[nt] = *(const f16x8*)&Xw[col * RSTR + 32 + kg * 8];
            f32x4 ac0 = {0.f,0.f,0.f,0.f}, ac1 = {0.f,0.f,0.f,0.f},
                  ac2 = {0.f,0.f,0.f,0.f}, ac3 = {0.f,0.f,0.f,0.f};
            ac0 = __builtin_amdgcn_mfma_f32_16x16x32_f16(Vf[0][0], xbA[nt], ac0, 0,0,0);
            ac0 = __builtin_amdgcn_mfma_f32_16x16x32_f16(Vf[0][1], xbB[nt], ac0, 0,0,0);
            ac1 = __builtin_amdgcn_mfma_f32_16x16x32_f16(Vf[1][0], xbA[nt], ac1, 0,0,0);
            ac1 = __builtin_amdgcn_mfma_f32_16x16x32_f16(Vf[1][1], xbB[nt], ac1, 0,0,0);
            ac2 = __builtin_amdgcn_mfma_f32_16x16x32_f16(Vf[2][0], xbA[nt], ac2, 0,0,0);
            ac2 = __builtin_amdgcn_mfma_f32_16x16x32_f16(Vf[2][1], xbB[nt], ac2, 0,0,0);
            ac3 = __builtin_amdgcn_mfma_f32_16x16x32_f16(Vf[3][0], xbA[nt], ac3, 0,0,0);
            ac3 = __builtin_amdgcn_mfma_f32_16x16x32_f16(Vf[3][1], xbB[nt], ac3, 0,0,0);
            const f32x4 a4[4] = {ac0, ac1, ac2, ac3};
#pragma unroll
            for (int mt = 0; mt < 4; ++mt) {
                f16x4 pv;
                pv[0] = (f16)a4[mt][0]; pv[1] = (f16)a4[mt][1];
                pv[2] = (f16)a4[mt][2]; pv[3] = (f16)a4[mt][3];
                *(f16x4*)&Xw[col * RSTR + mt * 16 + kg * 4] = pv;
            }
        }

        // ---- P6: diagonal recurrence over this segment's 32 chunks ----
        {
            const int j = l;
            for (int c0 = 0; c0 < SEG; c0 += 8) {
                float pv[8];
#pragma unroll
                for (int k2 = 0; k2 < 8; ++k2)
                    pv[k2] = (float)Xw[(c0 + k2) * RSTR + j];
#pragma unroll
                for (int k2 = 0; k2 < 8; ++k2) {
                    Xw[(c0 + k2) * RSTR + j] = (f16)u;   // u_in pre-update
                    const float usw = bfly1(u);
                    u = fmaf(lr, u, fmaf(lis, usw, pv[k2]));
                }
            }
        }

        // ---- P7: Y = T' @ X + M @ U, gelu -> tile (Tf/Mf streamed) ----
        {
            f16x8 ub0[2], ub1[2];
#pragma unroll
            for (int nt = 0; nt < 2; ++nt) {       // read ALL U before writes
                const int col = nt * 16 + row16;
                ub0[nt] = *(const f16x8*)&Xw[col * RSTR + kg * 8];
                ub1[nt] = *(const f16x8*)&Xw[col * RSTR + 32 + kg * 8];
            }
#pragma unroll
            for (int mt = 0; mt < 4; ++mt) {
                const size_t rT = (size_t)(mt * 16 + row16) * 64;
                const size_t rM = (size_t)(64 + mt * 16 + row16) * 64;
                const f16x8 Tf0 = *(const f16x8*)&Gh[rT + kg * 8];
                const f16x8 Tf1 = *(const f16x8*)&Gh[rT + 32 + kg * 8];
                const f16x8 Mf0 = *(const f16x8*)&Gh[rM + kg * 8];
                const f16x8 Mf1 = *(const f16x8*)&Gh[rM + 32 + kg * 8];
#pragma unroll
                for (int nt = 0; nt < 2; ++nt) {
                    const int col = nt * 16 + row16;
                    f32x4 ac = {0.f, 0.f, 0.f, 0.f};
                    ac = __builtin_amdgcn_mfma_f32_16x16x32_f16(Tf0, xbA[nt], ac, 0,0,0);
                    ac = __builtin_amdgcn_mfma_f32_16x16x32_f16(Tf1, xbB[nt], ac, 0,0,0);
                    ac = __builtin_amdgcn_mfma_f32_16x16x32_f16(Mf0, ub0[nt], ac, 0,0,0);
                    ac = __builtin_amdgcn_mfma_f32_16x16x32_f16(Mf1, ub1[nt], ac, 0,0,0);
                    const int t0 = mt * 16 + kg * 4;
                    f16x4 pk;
#pragma unroll
                    for (int r = 0; r < 4; ++r) {
                        const float yv = ac[r];    // D*x folded into T'
                        const float y2 = yv * yv;
                        const float arg = yv * fmaf(-0.10294502f, y2, -2.30218425f);
                        const float e   = __builtin_amdgcn_exp2f(arg);
                        pk[r] = (f16)(yv * __builtin_amdgcn_rcpf(1.0f + e));
                    }
                    *(f16x4*)&Xw[col * RSTR + t0] = pk;
                }
            }
        }
        __syncthreads();                           // Y in tiles

        // ---- cooperative Y store: full 64B lines ----
#pragma unroll
        for (int iter = 0; iter < 4; ++iter) {
            const int t0 = tbase + iter * 512 + tp * 2;
            const int c = (t0 >> 6) & (SEG - 1), s0 = t0 & 63;
            f32x4 v0, v1;
#pragma unroll
            for (int j = 0; j < 4; ++j) {
                const f16x2 p = *(const f16x2*)
                    &XT[((j << 2) | hq) * TSTR + c * RSTR + s0];
                v0[j] = (float)p[0]; v1[j] = (float)p[1];
            }
            *(f32x4*)&yb_[(size_t)t0 * H_]       = v0;
            *(f32x4*)&yb_[(size_t)(t0 + 1) * H_] = v1;
        }
        if (s == 0) __syncthreads();               // store reads done; reuse
    }

    // ---- final state (after segment 1's recurrence) ----
    {
        const int j = l, n = j >> 1;
        const int pairIdx = b * H_ + h;
        if ((j & 1) == 0) st_re[(size_t)pairIdx * N2_ + n] = u;
        else              st_im[(size_t)pairIdx * N2_ + n] = u;
    }
}

extern "C" void kernel_launch(void* const* d_in, const int* in_sizes, int n_in,
                              void* d_out, int out_size, void* d_ws, size_t ws_size,
                              hipStream_t stream) {
    (void)in_sizes; (void)n_in; (void)out_size; (void)ws_size;
    const float* x    = (const float*)d_in[0];
    const float* ldt  = (const float*)d_in[1];
    const float* Arl  = (const float*)d_in[2];
    const float* Aim  = (const float*)d_in[3];
    const float* Bre  = (const float*)d_in[4];
    const float* Bim  = (const float*)d_in[5];
    const float* Cre  = (const float*)d_in[6];
    const float* Cim  = (const float*)d_in[7];
    const float* Dv   = (const float*)d_in[8];
    float* out = (float*)d_out;
    float* st_re = out + (size_t)B_ * L_ * H_;       // ys first (64 MB)
    float* st_im = st_re + (size_t)B_ * H_ * N2_;    // then imag plane

    // G f16 (12.6 MB) + Lg f32 (131 KB) live in the workspace.
    f16*   G  = (f16*)d_ws;
    float* Lg = (float*)((char*)d_ws + (size_t)H_ * 192 * 64 * 2);

    hipLaunchKernelGGL(k_build, dim3(H_), dim3(256), 0, stream,
                       ldt, Arl, Aim, Bre, Bim, Cre, Cim, Dv, G, Lg);
    hipLaunchKernelGGL(s4d_conv_kernel, dim3(256), dim3(1024), 0, stream,
                       x, G, Lg, out, st_re, st_im);
}

// Round 20
// 213.291 us; speedup vs baseline: 1.3214x; 1.3214x over previous
//
#include <hip/hip_runtime.h>
#include <math.h>

// S4D — round 26: r25 (segmented 2-half convolution, 74 KB LDS) with the
// register clamp REVERTED: __launch_bounds__(1024,4), not (1024,8).
// r25's (1024,8) forced VGPR=32 -> massive scratch spill (FETCH 201 MB,
// WRITE 256 MB, conv 180us). With (1024,4) the allocator has 128 budget;
// r24's heavier body compiled to exactly 64, and the segmented body is
// lighter (xbA/xbB halved), so it should land <=64 naturally — at which
// point the HW schedules 2 blocks/CU from the 74 KB LDS footprint and the
// stage/compute phases of the two blocks overlap. Worst case (>64 VGPR)
// we get r24's 1-block behavior, no spill.

#define H_  512
#define L_  4096
#define B_  8
#define N2_ 32
#define NC  64            // total chunks of 64 timesteps
#define SEG 32            // chunks per segment
#define RSTR 72           // tile inner row stride, f16 units (144 B)
#define TSTR 2320         // f16 per tile slot: 32*72 + 16 pad (4640 B)

typedef _Float16 f16;
typedef _Float16 f16x8 __attribute__((ext_vector_type(8)));
typedef _Float16 f16x4 __attribute__((ext_vector_type(4)));
typedef _Float16 f16x2 __attribute__((ext_vector_type(2)));
typedef float    f32x4 __attribute__((ext_vector_type(4)));

__device__ __forceinline__ float bfly1(float v) {   // xor 1: quad_perm [1,0,3,2]
    return __int_as_float(__builtin_amdgcn_update_dpp(
        0, __float_as_int(v), 0xB1, 0xf, 0xf, true));
}

// ---------------- kernel D: per-h matrix build (r22-r25, verified) ---------
// G[h][192][64] f16: T'(+D diag) rows 0..63, M 64..127, V 128..191.
// Lg[h][64] f32: Λ re [0:32), im [32:64).
__global__ __launch_bounds__(256) void k_build(
    const float* __restrict__ log_dt,
    const float* __restrict__ A_real_log,
    const float* __restrict__ A_imag,
    const float* __restrict__ B_re,
    const float* __restrict__ B_im,
    const float* __restrict__ C_re,
    const float* __restrict__ C_im,
    const float* __restrict__ Dv,
    f16*  __restrict__ G,
    float* __restrict__ Lg)
{
    __shared__ float pr[32 * 66], pi[32 * 66];     // dApow [n][66], p=0..64
    __shared__ float s_xr[32], s_xi[32], s_dBr[32], s_dBi[32],
                     s_wr[32], s_wi[32], s_wdr[32], s_wdi[32], s_k[64];
    const int h   = (int)blockIdx.x;
    const int tid = threadIdx.x;

    if (tid < 32) {
        const int n = tid, hn = h * N2_ + n;
        const float dt = expf(log_dt[h]);
        const float Ar = -expf(A_real_log[hn]);
        const float Ai = A_imag[hn];
        const float xr = dt * Ar, xi = dt * Ai;
        s_xr[n] = xr; s_xi[n] = xi;
        const float ex = expf(xr), cs = cosf(xi), sn = sinf(xi);
        const float sh  = sinf(0.5f * xi);
        const float emr = expm1f(xr) * cs - 2.0f * sh * sh;  // Re(expm1(dtA))
        const float emi = ex * sn;
        const float ia  = 1.0f / (Ar * Ar + Ai * Ai);
        const float tr  = (emr * Ar + emi * Ai) * ia;
        const float ti  = (emi * Ar - emr * Ai) * ia;
        const float Brv = B_re[hn], Biv = B_im[hn];
        const float dBr = Brv * tr - Biv * ti, dBi = Brv * ti + Biv * tr;
        s_dBr[n] = dBr; s_dBi[n] = dBi;
        const float wr = 2.0f * C_re[hn], wi = 2.0f * C_im[hn];
        s_wr[n] = wr; s_wi[n] = wi;
        s_wdr[n] = wr * dBr - wi * dBi;             // w*dB
        s_wdi[n] = wr * dBi + wi * dBr;
    }
    __syncthreads();

    for (int e = tid; e < 2048; e += 256) {         // p = 0..63
        const int n = e >> 6, p = e & 63;
        const float ex = expf((float)p * s_xr[n]);
        float sn, cs; sincosf((float)p * s_xi[n], &sn, &cs);
        pr[n * 66 + p] = ex * cs; pi[n * 66 + p] = ex * sn;
    }
    if (tid < 32) {                                 // p = 64
        const int n = tid;
        const float ex = expf(64.f * s_xr[n]);
        float sn, cs; sincosf(64.f * s_xi[n], &sn, &cs);
        pr[n * 66 + 64] = ex * cs; pi[n * 66 + 64] = ex * sn;
    }
    __syncthreads();

    if (tid < 64) {                                 // k[d] = Re(w dB dA^d)
        float acc = 0.f;
        for (int n = 0; n < 32; ++n)
            acc += s_wdr[n] * pr[n * 66 + tid] - s_wdi[n] * pi[n * 66 + tid];
        s_k[tid] = acc;
    }
    if (tid < 32) {                                 // Λ = dA^64
        Lg[h * 64 + tid]      = pr[tid * 66 + 64];
        Lg[h * 64 + 32 + tid] = pi[tid * 66 + 64];
    }
    const float Dh = Dv[h];
    f16* Gh = G + (size_t)h * 192 * 64;
    for (int e = tid; e < 4096; e += 256) {         // M rows 64..127
        const int t = e >> 6, j = e & 63, n = j >> 1;
        const float re = pr[n * 66 + t + 1], im = pi[n * 66 + t + 1];
        const float mv = (j & 1) ? -(s_wr[n] * im + s_wi[n] * re)
                                 :  (s_wr[n] * re - s_wi[n] * im);
        Gh[(size_t)(64 + t) * 64 + j] = (f16)mv;
    }
    for (int e = tid; e < 4096; e += 256) {         // V rows 128..191
        const int r = e >> 6, s = e & 63, n = r >> 1;
        const float re = pr[n * 66 + 63 - s], im = pi[n * 66 + 63 - s];
        const float vv = (r & 1) ? (s_dBr[n] * im + s_dBi[n] * re)
                                 : (s_dBr[n] * re - s_dBi[n] * im);
        Gh[(size_t)(128 + r) * 64 + s] = (f16)vv;
    }
    __syncthreads();                                // s_k ready for all
    for (int e = tid; e < 4096; e += 256) {         // T' rows 0..63 (+D diag)
        const int t = e >> 6, s = e & 63;
        const float tv = (s <= t) ? (s_k[t - s] + (s == t ? Dh : 0.f)) : 0.f;
        Gh[(size_t)t * 64 + s] = (f16)tv;
    }
}

// ---------------- kernel B: segmented full-line direct-IO convolution ------
__global__ __launch_bounds__(1024, 4) void s4d_conv_kernel(
    const float* __restrict__ x,          // (B, L, H) f32
    const f16*  __restrict__ G,           // (H, 192, 64) f16: T'/M/V
    const float* __restrict__ Lg,         // (H, 64) f32: Λ re|im
    float* __restrict__ y,                // (B, L, H) f32 (gelu'd)
    float* __restrict__ st_re,            // (B, H, N2)
    float* __restrict__ st_im)            // (B, H, N2)
{
    __shared__ f16 XT[16 * TSTR];                  // 74,240 B: 16 wave tiles

    // XCD swizzle: XCD k owns h-groups [4k,4k+4), all b.
    const int bid = (int)blockIdx.x;               // 0..255
    const int lb  = (bid & 7) * 32 + (bid >> 3);
    const int hg  = lb >> 3;                       // 0..31 (16-h group)
    const int b   = lb & 7;

    const int tid = threadIdx.x;
    const int l   = tid & 63;
    const int w   = tid >> 6;                      // wave -> h = hg*16 + w
    const int h   = hg * 16 + w;
    const int row16 = l & 15, kg = l >> 4;

    const f16* Gh = G + (size_t)h * 192 * 64;

    // ---- Vf preload (global, L2-resident) + Λ ----
    f16x8 Vf[4][2];
#pragma unroll
    for (int mt = 0; mt < 4; ++mt)
#pragma unroll
        for (int ks = 0; ks < 2; ++ks)
            Vf[mt][ks] = *(const f16x8*)
                &Gh[(size_t)(128 + mt * 16 + row16) * 64 + ks * 32 + kg * 8];
    const float lr  = Lg[h * 64 + (l >> 1)];
    const float li0 = Lg[h * 64 + 32 + (l >> 1)];
    const float lis = (l & 1) ? li0 : -li0;

    const int hq = tid & 3;                        // staging: h sub-quad
    const int tp = tid >> 2;                       // t-pair index 0..255
    const float* xb_ = x + (size_t)b * L_ * H_ + hg * 16 + hq * 4;
    float*       yb_ = y + (size_t)b * L_ * H_ + hg * 16 + hq * 4;
    f16* Xw = &XT[(((w & 3) << 2) | (w >> 2)) * TSTR];   // PHYS(w)

    float u = 0.f;                                 // recurrence state (j = l)

    for (int s = 0; s < 2; ++s) {
        const int tbase = s * (SEG * 64);          // 0 or 2048

        // ---- cooperative X staging: lane-quad = one FULL 64B line ----
#pragma unroll
        for (int iter = 0; iter < 4; ++iter) {
            const int t0 = tbase + iter * 512 + tp * 2;
            const f32x4 v0 = *(const f32x4*)&xb_[(size_t)t0 * H_];
            const f32x4 v1 = *(const f32x4*)&xb_[(size_t)(t0 + 1) * H_];
            const int c = (t0 >> 6) & (SEG - 1), s0 = t0 & 63;
#pragma unroll
            for (int j = 0; j < 4; ++j) {          // h_local = hq*4+j
                f16x2 p; p[0] = (f16)v0[j]; p[1] = (f16)v1[j];
                *(f16x2*)&XT[((j << 2) | hq) * TSTR + c * RSTR + s0] = p;
            }
        }
        __syncthreads();                           // X staged

        // ---- P5: P = V @ X; X fragments stay live for P7 ----
        f16x8 xbA[2], xbB[2];
#pragma unroll
        for (int nt = 0; nt < 2; ++nt) {
            const int col = nt * 16 + row16;
            xbA[nt] = *(const f16x8*)&Xw[col * RSTR + kg * 8];
            xbB[nt] = *(const f16x8*)&Xw[col * RSTR + 32 + kg * 8];
            f32x4 ac0 = {0.f,0.f,0.f,0.f}, ac1 = {0.f,0.f,0.f,0.f},
                  ac2 = {0.f,0.f,0.f,0.f}, ac3 = {0.f,0.f,0.f,0.f};
            ac0 = __builtin_amdgcn_mfma_f32_16x16x32_f16(Vf[0][0], xbA[nt], ac0, 0,0,0);
            ac0 = __builtin_amdgcn_mfma_f32_16x16x32_f16(Vf[0][1], xbB[nt], ac0, 0,0,0);
            ac1 = __builtin_amdgcn_mfma_f32_16x16x32_f16(Vf[1][0], xbA[nt], ac1, 0,0,0);
            ac1 = __builtin_amdgcn_mfma_f32_16x16x32_f16(Vf[1][1], xbB[nt], ac1, 0,0,0);
            ac2 = __builtin_amdgcn_mfma_f32_16x16x32_f16(Vf[2][0], xbA[nt], ac2, 0,0,0);
            ac2 = __builtin_amdgcn_mfma_f32_16x16x32_f16(Vf[2][1], xbB[nt], ac2, 0,0,0);
            ac3 = __builtin_amdgcn_mfma_f32_16x16x32_f16(Vf[3][0], xbA[nt], ac3, 0,0,0);
            ac3 = __builtin_amdgcn_mfma_f32_16x16x32_f16(Vf[3][1], xbB[nt], ac3, 0,0,0);
            const f32x4 a4[4] = {ac0, ac1, ac2, ac3};
#pragma unroll
            for (int mt = 0; mt < 4; ++mt) {
                f16x4 pv;
                pv[0] = (f16)a4[mt][0]; pv[1] = (f16)a4[mt][1];
                pv[2] = (f16)a4[mt][2]; pv[3] = (f16)a4[mt][3];
                *(f16x4*)&Xw[col * RSTR + mt * 16 + kg * 4] = pv;
            }
        }

        // ---- P6: diagonal recurrence over this segment's 32 chunks ----
        {
            const int j = l;
            for (int c0 = 0; c0 < SEG; c0 += 8) {
                float pv[8];
#pragma unroll
                for (int k2 = 0; k2 < 8; ++k2)
                    pv[k2] = (float)Xw[(c0 + k2) * RSTR + j];
#pragma unroll
                for (int k2 = 0; k2 < 8; ++k2) {
                    Xw[(c0 + k2) * RSTR + j] = (f16)u;   // u_in pre-update
                    const float usw = bfly1(u);
                    u = fmaf(lr, u, fmaf(lis, usw, pv[k2]));
                }
            }
        }

        // ---- P7: Y = T' @ X + M @ U, gelu -> tile (Tf/Mf streamed) ----
        {
            f16x8 ub0[2], ub1[2];
#pragma unroll
            for (int nt = 0; nt < 2; ++nt) {       // read ALL U before writes
                const int col = nt * 16 + row16;
                ub0[nt] = *(const f16x8*)&Xw[col * RSTR + kg * 8];
                ub1[nt] = *(const f16x8*)&Xw[col * RSTR + 32 + kg * 8];
            }
#pragma unroll
            for (int mt = 0; mt < 4; ++mt) {
                const size_t rT = (size_t)(mt * 16 + row16) * 64;
                const size_t rM = (size_t)(64 + mt * 16 + row16) * 64;
                const f16x8 Tf0 = *(const f16x8*)&Gh[rT + kg * 8];
                const f16x8 Tf1 = *(const f16x8*)&Gh[rT + 32 + kg * 8];
                const f16x8 Mf0 = *(const f16x8*)&Gh[rM + kg * 8];
                const f16x8 Mf1 = *(const f16x8*)&Gh[rM + 32 + kg * 8];
#pragma unroll
                for (int nt = 0; nt < 2; ++nt) {
                    const int col = nt * 16 + row16;
                    f32x4 ac = {0.f, 0.f, 0.f, 0.f};
                    ac = __builtin_amdgcn_mfma_f32_16x16x32_f16(Tf0, xbA[nt], ac, 0,0,0);
                    ac = __builtin_amdgcn_mfma_f32_16x16x32_f16(Tf1, xbB[nt], ac, 0,0,0);
                    ac = __builtin_amdgcn_mfma_f32_16x16x32_f16(Mf0, ub0[nt], ac, 0,0,0);
                    ac = __builtin_amdgcn_mfma_f32_16x16x32_f16(Mf1, ub1[nt], ac, 0,0,0);
                    const int t0 = mt * 16 + kg * 4;
                    f16x4 pk;
#pragma unroll
                    for (int r = 0; r < 4; ++r) {
                        const float yv = ac[r];    // D*x folded into T'
                        const float y2 = yv * yv;
                        const float arg = yv * fmaf(-0.10294502f, y2, -2.30218425f);
                        const float e   = __builtin_amdgcn_exp2f(arg);
                        pk[r] = (f16)(yv * __builtin_amdgcn_rcpf(1.0f + e));
                    }
                    *(f16x4*)&Xw[col * RSTR + t0] = pk;
                }
            }
        }
        __syncthreads();                           // Y in tiles

        // ---- cooperative Y store: full 64B lines ----
#pragma unroll
        for (int iter = 0; iter < 4; ++iter) {
            const int t0 = tbase + iter * 512 + tp * 2;
            const int c = (t0 >> 6) & (SEG - 1), s0 = t0 & 63;
            f32x4 v0, v1;
#pragma unroll
            for (int j = 0; j < 4; ++j) {
                const f16x2 p = *(const f16x2*)
                    &XT[((j << 2) | hq) * TSTR + c * RSTR + s0];
                v0[j] = (float)p[0]; v1[j] = (float)p[1];
            }
            *(f32x4*)&yb_[(size_t)t0 * H_]       = v0;
            *(f32x4*)&yb_[(size_t)(t0 + 1) * H_] = v1;
        }
        if (s == 0) __syncthreads();               // store reads done; reuse
    }

    // ---- final state (after segment 1's recurrence) ----
    {
        const int j = l, n = j >> 1;
        const int pairIdx = b * H_ + h;
        if ((j & 1) == 0) st_re[(size_t)pairIdx * N2_ + n] = u;
        else              st_im[(size_t)pairIdx * N2_ + n] = u;
    }
}

extern "C" void kernel_launch(void* const* d_in, const int* in_sizes, int n_in,
                              void* d_out, int out_size, void* d_ws, size_t ws_size,
                              hipStream_t stream) {
    (void)in_sizes; (void)n_in; (void)out_size; (void)ws_size;
    const float* x    = (const float*)d_in[0];
    const float* ldt  = (const float*)d_in[1];
    const float* Arl  = (const float*)d_in[2];
    const float* Aim  = (const float*)d_in[3];
    const float* Bre  = (const float*)d_in[4];
    const float* Bim  = (const float*)d_in[5];
    const float* Cre  = (const float*)d_in[6];
    const float* Cim  = (const float*)d_in[7];
    const float* Dv   = (const float*)d_in[8];
    float* out = (float*)d_out;
    float* st_re = out + (size_t)B_ * L_ * H_;       // ys first (64 MB)
    float* st_im = st_re + (size_t)B_ * H_ * N2_;    // then imag plane

    // G f16 (12.6 MB) + Lg f32 (131 KB) live in the workspace.
    f16*   G  = (f16*)d_ws;
    float* Lg = (float*)((char*)d_ws + (size_t)H_ * 192 * 64 * 2);

    hipLaunchKernelGGL(k_build, dim3(H_), dim3(256), 0, stream,
                       ldt, Arl, Aim, Bre, Bim, Cre, Cim, Dv, G, Lg);
    hipLaunchKernelGGL(s4d_conv_kernel, dim3(256), dim3(1024), 0, stream,
                       x, G, Lg, out, st_re, st_im);
}

// Round 21
// 207.213 us; speedup vs baseline: 1.3602x; 1.0293x over previous
//
#include <hip/hip_runtime.h>
#include <math.h>

// S4D — round 27: single-block two-segment software pipeline.
// r26 lesson: 2 blocks/CU requires <=64 VGPR (HW), body needs ~80 -> spill
// (FETCH 110/WRITE 145 MB scratch traffic). So force 1 block/CU with
// DISJOINT LDS halves (2 x 74.2 KB = 148.5 KB -> compiler targets 4
// waves/SIMD -> 128 VGPR budget, no spill) and overlap INSIDE the block:
//   stage seg0->LDS0; B1; issue seg1 loads->regs (in flight);
//   compute seg0 (hides load latency); write LDS1; B2;
//   store y0 (fire-and-forget); compute seg1; B3; store y1.
// y0's store drain hides under seg1 compute; seg1's x-load latency hides
// under seg0 compute. vs r24's serial stage->compute->store.

#define H_  512
#define L_  4096
#define B_  8
#define N2_ 32
#define SEG 32            // chunks per segment
#define RSTR 72           // tile inner row stride, f16 units (144 B)
#define TSTR 2320         // f16 per tile slot: 32*72 + 16 pad (4640 B)

typedef _Float16 f16;
typedef _Float16 f16x8 __attribute__((ext_vector_type(8)));
typedef _Float16 f16x4 __attribute__((ext_vector_type(4)));
typedef _Float16 f16x2 __attribute__((ext_vector_type(2)));
typedef float    f32x4 __attribute__((ext_vector_type(4)));

__device__ __forceinline__ float bfly1(float v) {   // xor 1: quad_perm [1,0,3,2]
    return __int_as_float(__builtin_amdgcn_update_dpp(
        0, __float_as_int(v), 0xB1, 0xf, 0xf, true));
}

// ---------------- kernel D: per-h matrix build (r22-r26, verified) ---------
// G[h][192][64] f16: T'(+D diag) rows 0..63, M 64..127, V 128..191.
// Lg[h][64] f32: Λ re [0:32), im [32:64).
__global__ __launch_bounds__(256) void k_build(
    const float* __restrict__ log_dt,
    const float* __restrict__ A_real_log,
    const float* __restrict__ A_imag,
    const float* __restrict__ B_re,
    const float* __restrict__ B_im,
    const float* __restrict__ C_re,
    const float* __restrict__ C_im,
    const float* __restrict__ Dv,
    f16*  __restrict__ G,
    float* __restrict__ Lg)
{
    __shared__ float pr[32 * 66], pi[32 * 66];     // dApow [n][66], p=0..64
    __shared__ float s_xr[32], s_xi[32], s_dBr[32], s_dBi[32],
                     s_wr[32], s_wi[32], s_wdr[32], s_wdi[32], s_k[64];
    const int h   = (int)blockIdx.x;
    const int tid = threadIdx.x;

    if (tid < 32) {
        const int n = tid, hn = h * N2_ + n;
        const float dt = expf(log_dt[h]);
        const float Ar = -expf(A_real_log[hn]);
        const float Ai = A_imag[hn];
        const float xr = dt * Ar, xi = dt * Ai;
        s_xr[n] = xr; s_xi[n] = xi;
        const float ex = expf(xr), cs = cosf(xi), sn = sinf(xi);
        const float sh  = sinf(0.5f * xi);
        const float emr = expm1f(xr) * cs - 2.0f * sh * sh;  // Re(expm1(dtA))
        const float emi = ex * sn;
        const float ia  = 1.0f / (Ar * Ar + Ai * Ai);
        const float tr  = (emr * Ar + emi * Ai) * ia;
        const float ti  = (emi * Ar - emr * Ai) * ia;
        const float Brv = B_re[hn], Biv = B_im[hn];
        const float dBr = Brv * tr - Biv * ti, dBi = Brv * ti + Biv * tr;
        s_dBr[n] = dBr; s_dBi[n] = dBi;
        const float wr = 2.0f * C_re[hn], wi = 2.0f * C_im[hn];
        s_wr[n] = wr; s_wi[n] = wi;
        s_wdr[n] = wr * dBr - wi * dBi;             // w*dB
        s_wdi[n] = wr * dBi + wi * dBr;
    }
    __syncthreads();

    for (int e = tid; e < 2048; e += 256) {         // p = 0..63
        const int n = e >> 6, p = e & 63;
        const float ex = expf((float)p * s_xr[n]);
        float sn, cs; sincosf((float)p * s_xi[n], &sn, &cs);
        pr[n * 66 + p] = ex * cs; pi[n * 66 + p] = ex * sn;
    }
    if (tid < 32) {                                 // p = 64
        const int n = tid;
        const float ex = expf(64.f * s_xr[n]);
        float sn, cs; sincosf(64.f * s_xi[n], &sn, &cs);
        pr[n * 66 + 64] = ex * cs; pi[n * 66 + 64] = ex * sn;
    }
    __syncthreads();

    if (tid < 64) {                                 // k[d] = Re(w dB dA^d)
        float acc = 0.f;
        for (int n = 0; n < 32; ++n)
            acc += s_wdr[n] * pr[n * 66 + tid] - s_wdi[n] * pi[n * 66 + tid];
        s_k[tid] = acc;
    }
    if (tid < 32) {                                 // Λ = dA^64
        Lg[h * 64 + tid]      = pr[tid * 66 + 64];
        Lg[h * 64 + 32 + tid] = pi[tid * 66 + 64];
    }
    const float Dh = Dv[h];
    f16* Gh = G + (size_t)h * 192 * 64;
    for (int e = tid; e < 4096; e += 256) {         // M rows 64..127
        const int t = e >> 6, j = e & 63, n = j >> 1;
        const float re = pr[n * 66 + t + 1], im = pi[n * 66 + t + 1];
        const float mv = (j & 1) ? -(s_wr[n] * im + s_wi[n] * re)
                                 :  (s_wr[n] * re - s_wi[n] * im);
        Gh[(size_t)(64 + t) * 64 + j] = (f16)mv;
    }
    for (int e = tid; e < 4096; e += 256) {         // V rows 128..191
        const int r = e >> 6, s = e & 63, n = r >> 1;
        const float re = pr[n * 66 + 63 - s], im = pi[n * 66 + 63 - s];
        const float vv = (r & 1) ? (s_dBr[n] * im + s_dBi[n] * re)
                                 : (s_dBr[n] * re - s_dBi[n] * im);
        Gh[(size_t)(128 + r) * 64 + s] = (f16)vv;
    }
    __syncthreads();                                // s_k ready for all
    for (int e = tid; e < 4096; e += 256) {         // T' rows 0..63 (+D diag)
        const int t = e >> 6, s = e & 63;
        const float tv = (s <= t) ? (s_k[t - s] + (s == t ? Dh : 0.f)) : 0.f;
        Gh[(size_t)t * 64 + s] = (f16)tv;
    }
}

// ---------------- kernel B: pipelined full-line direct-IO convolution ------
__global__ __launch_bounds__(1024, 4) void s4d_conv_kernel(
    const float* __restrict__ x,          // (B, L, H) f32
    const f16*  __restrict__ G,           // (H, 192, 64) f16: T'/M/V
    const float* __restrict__ Lg,         // (H, 64) f32: Λ re|im
    float* __restrict__ y,                // (B, L, H) f32 (gelu'd)
    float* __restrict__ st_re,            // (B, H, N2)
    float* __restrict__ st_im)            // (B, H, N2)
{
    __shared__ f16 XT[2][16 * TSTR];               // 148,480 B: 2 seg-halves

    // XCD swizzle: XCD k owns h-groups [4k,4k+4), all b.
    const int bid = (int)blockIdx.x;               // 0..255
    const int lb  = (bid & 7) * 32 + (bid >> 3);
    const int hg  = lb >> 3;                       // 0..31 (16-h group)
    const int b   = lb & 7;

    const int tid = threadIdx.x;
    const int l   = tid & 63;
    const int w   = tid >> 6;                      // wave -> h = hg*16 + w
    const int h   = hg * 16 + w;
    const int row16 = l & 15, kg = l >> 4;

    const f16* Gh = G + (size_t)h * 192 * 64;

    // ---- Vf preload (global, L2-resident) + Λ ----
    f16x8 Vf[4][2];
#pragma unroll
    for (int mt = 0; mt < 4; ++mt)
#pragma unroll
        for (int ks = 0; ks < 2; ++ks)
            Vf[mt][ks] = *(const f16x8*)
                &Gh[(size_t)(128 + mt * 16 + row16) * 64 + ks * 32 + kg * 8];
    const float lr  = Lg[h * 64 + (l >> 1)];
    const float li0 = Lg[h * 64 + 32 + (l >> 1)];
    const float lis = (l & 1) ? li0 : -li0;

    const int hq = tid & 3;                        // staging: h sub-quad
    const int tp = tid >> 2;                       // t-pair index 0..255
    const float* xb_ = x + (size_t)b * L_ * H_ + hg * 16 + hq * 4;
    float*       yb_ = y + (size_t)b * L_ * H_ + hg * 16 + hq * 4;
    const int physw = (((w & 3) << 2) | (w >> 2)) * TSTR;    // PHYS(w)

    float u = 0.f;                                 // recurrence state (j = l)

    // ================= stage seg0 -> LDS0 =================
#pragma unroll
    for (int iter = 0; iter < 4; ++iter) {
        const int t0 = iter * 512 + tp * 2;
        const f32x4 v0 = *(const f32x4*)&xb_[(size_t)t0 * H_];
        const f32x4 v1 = *(const f32x4*)&xb_[(size_t)(t0 + 1) * H_];
        const int c = (t0 >> 6) & (SEG - 1), s0 = t0 & 63;
#pragma unroll
        for (int j = 0; j < 4; ++j) {
            f16x2 p; p[0] = (f16)v0[j]; p[1] = (f16)v1[j];
            *(f16x2*)&XT[0][((j << 2) | hq) * TSTR + c * RSTR + s0] = p;
        }
    }
    __syncthreads();                               // B1: X0 staged

    // ---- issue seg1 global loads (fly under seg0 compute) ----
    f32x4 rA[4], rB[4];
#pragma unroll
    for (int iter = 0; iter < 4; ++iter) {
        const int t0 = 2048 + iter * 512 + tp * 2;
        rA[iter] = *(const f32x4*)&xb_[(size_t)t0 * H_];
        rB[iter] = *(const f32x4*)&xb_[(size_t)(t0 + 1) * H_];
    }

    // ================= compute macro (one segment) =================
#define COMPUTE_SEG(XHALF)                                                     \
    {                                                                          \
        f16* Xw = &XT[XHALF][physw];                                           \
        f16x8 xbA[2], xbB[2];                                                  \
        _Pragma("unroll")                                                      \
        for (int nt = 0; nt < 2; ++nt) {                                       \
            const int col = nt * 16 + row16;                                   \
            xbA[nt] = *(const f16x8*)&Xw[col * RSTR + kg * 8];                 \
            xbB[nt] = *(const f16x8*)&Xw[col * RSTR + 32 + kg * 8];            \
            f32x4 ac0 = {0.f,0.f,0.f,0.f}, ac1 = {0.f,0.f,0.f,0.f},            \
                  ac2 = {0.f,0.f,0.f,0.f}, ac3 = {0.f,0.f,0.f,0.f};            \
            ac0 = __builtin_amdgcn_mfma_f32_16x16x32_f16(Vf[0][0], xbA[nt], ac0, 0,0,0); \
            ac0 = __builtin_amdgcn_mfma_f32_16x16x32_f16(Vf[0][1], xbB[nt], ac0, 0,0,0); \
            ac1 = __builtin_amdgcn_mfma_f32_16x16x32_f16(Vf[1][0], xbA[nt], ac1, 0,0,0); \
            ac1 = __builtin_amdgcn_mfma_f32_16x16x32_f16(Vf[1][1], xbB[nt], ac1, 0,0,0); \
            ac2 = __builtin_amdgcn_mfma_f32_16x16x32_f16(Vf[2][0], xbA[nt], ac2, 0,0,0); \
            ac2 = __builtin_amdgcn_mfma_f32_16x16x32_f16(Vf[2][1], xbB[nt], ac2, 0,0,0); \
            ac3 = __builtin_amdgcn_mfma_f32_16x16x32_f16(Vf[3][0], xbA[nt], ac3, 0,0,0); \
            ac3 = __builtin_amdgcn_mfma_f32_16x16x32_f16(Vf[3][1], xbB[nt], ac3, 0,0,0); \
            const f32x4 a4[4] = {ac0, ac1, ac2, ac3};                          \
            _Pragma("unroll")                                                  \
            for (int mt = 0; mt < 4; ++mt) {                                   \
                f16x4 pv;                                                      \
                pv[0] = (f16)a4[mt][0]; pv[1] = (f16)a4[mt][1];                \
                pv[2] = (f16)a4[mt][2]; pv[3] = (f16)a4[mt][3];                \
                *(f16x4*)&Xw[col * RSTR + mt * 16 + kg * 4] = pv;              \
            }                                                                  \
        }                                                                      \
        {   /* P6: diagonal recurrence over this segment's 32 chunks */        \
            const int j = l;                                                   \
            for (int c0 = 0; c0 < SEG; c0 += 8) {                              \
                float pv[8];                                                   \
                _Pragma("unroll")                                              \
                for (int k2 = 0; k2 < 8; ++k2)                                 \
                    pv[k2] = (float)Xw[(c0 + k2) * RSTR + j];                  \
                _Pragma("unroll")                                              \
                for (int k2 = 0; k2 < 8; ++k2) {                               \
                    Xw[(c0 + k2) * RSTR + j] = (f16)u;                         \
                    const float usw = bfly1(u);                                \
                    u = fmaf(lr, u, fmaf(lis, usw, pv[k2]));                   \
                }                                                              \
            }                                                                  \
        }                                                                      \
        {   /* P7: Y = T'@X + M@U, gelu -> tile (Tf/Mf streamed) */            \
            f16x8 ub0[2], ub1[2];                                              \
            _Pragma("unroll")                                                  \
            for (int nt = 0; nt < 2; ++nt) {                                   \
                const int col = nt * 16 + row16;                               \
                ub0[nt] = *(const f16x8*)&Xw[col * RSTR + kg * 8];             \
                ub1[nt] = *(const f16x8*)&Xw[col * RSTR + 32 + kg * 8];        \
            }                                                                  \
            _Pragma("unroll")                                                  \
            for (int mt = 0; mt < 4; ++mt) {                                   \
                const size_t rT = (size_t)(mt * 16 + row16) * 64;              \
                const size_t rM = (size_t)(64 + mt * 16 + row16) * 64;         \
                const f16x8 Tf0 = *(const f16x8*)&Gh[rT + kg * 8];             \
                const f16x8 Tf1 = *(const f16x8*)&Gh[rT + 32 + kg * 8];        \
                const f16x8 Mf0 = *(const f16x8*)&Gh[rM + kg * 8];             \
                const f16x8 Mf1 = *(const f16x8*)&Gh[rM + 32 + kg * 8];        \
                _Pragma("unroll")                                              \
                for (int nt = 0; nt < 2; ++nt) {                               \
                    const int col = nt * 16 + row16;                           \
                    f32x4 ac = {0.f, 0.f, 0.f, 0.f};                           \
                    ac = __builtin_amdgcn_mfma_f32_16x16x32_f16(Tf0, xbA[nt], ac, 0,0,0); \
                    ac = __builtin_amdgcn_mfma_f32_16x16x32_f16(Tf1, xbB[nt], ac, 0,0,0); \
                    ac = __builtin_amdgcn_mfma_f32_16x16x32_f16(Mf0, ub0[nt], ac, 0,0,0); \
                    ac = __builtin_amdgcn_mfma_f32_16x16x32_f16(Mf1, ub1[nt], ac, 0,0,0); \
                    const int t0 = mt * 16 + kg * 4;                           \
                    f16x4 pk;                                                  \
                    _Pragma("unroll")                                          \
                    for (int r = 0; r < 4; ++r) {                              \
                        const float yv = ac[r];                                \
                        const float y2 = yv * yv;                              \
                        const float arg = yv * fmaf(-0.10294502f, y2, -2.30218425f); \
                        const float e   = __builtin_amdgcn_exp2f(arg);         \
                        pk[r] = (f16)(yv * __builtin_amdgcn_rcpf(1.0f + e));   \
                    }                                                          \
                    *(f16x4*)&Xw[col * RSTR + t0] = pk;                        \
                }                                                              \
            }                                                                  \
        }                                                                      \
    }

#define STORE_SEG(XHALF, TBASE)                                                \
    {                                                                          \
        _Pragma("unroll")                                                      \
        for (int iter = 0; iter < 4; ++iter) {                                 \
            const int t0 = (TBASE) + iter * 512 + tp * 2;                      \
            const int c = (t0 >> 6) & (SEG - 1), s0 = t0 & 63;                 \
            f32x4 v0, v1;                                                      \
            _Pragma("unroll")                                                  \
            for (int j = 0; j < 4; ++j) {                                      \
                const f16x2 p = *(const f16x2*)                                \
                    &XT[XHALF][((j << 2) | hq) * TSTR + c * RSTR + s0];        \
                v0[j] = (float)p[0]; v1[j] = (float)p[1];                      \
            }                                                                  \
            *(f32x4*)&yb_[(size_t)t0 * H_]       = v0;                         \
            *(f32x4*)&yb_[(size_t)(t0 + 1) * H_] = v1;                         \
        }                                                                      \
    }

    // ================= pipeline =================
    COMPUTE_SEG(0)                                 // y0 into LDS0 (loads fly)

    // write seg1 -> LDS1 (waits only the rA/rB loads)
#pragma unroll
    for (int iter = 0; iter < 4; ++iter) {
        const int t0 = 2048 + iter * 512 + tp * 2;
        const int c = (t0 >> 6) & (SEG - 1), s0 = t0 & 63;
#pragma unroll
        for (int j = 0; j < 4; ++j) {
            f16x2 p; p[0] = (f16)rA[iter][j]; p[1] = (f16)rB[iter][j];
            *(f16x2*)&XT[1][((j << 2) | hq) * TSTR + c * RSTR + s0] = p;
        }
    }
    __syncthreads();                               // B2: y0 done + X1 staged

    STORE_SEG(0, 0)                                // fire-and-forget
    COMPUTE_SEG(1)                                 // y1 into LDS1
    __syncthreads();                               // B3: y1 done in tiles
    STORE_SEG(1, 2048)

    // ---- final state ----
    {
        const int j = l, n = j >> 1;
        const int pairIdx = b * H_ + h;
        if ((j & 1) == 0) st_re[(size_t)pairIdx * N2_ + n] = u;
        else              st_im[(size_t)pairIdx * N2_ + n] = u;
    }
#undef COMPUTE_SEG
#undef STORE_SEG
}

extern "C" void kernel_launch(void* const* d_in, const int* in_sizes, int n_in,
                              void* d_out, int out_size, void* d_ws, size_t ws_size,
                              hipStream_t stream) {
    (void)in_sizes; (void)n_in; (void)out_size; (void)ws_size;
    const float* x    = (const float*)d_in[0];
    const float* ldt  = (const float*)d_in[1];
    const float* Arl  = (const float*)d_in[2];
    const float* Aim  = (const float*)d_in[3];
    const float* Bre  = (const float*)d_in[4];
    const float* Bim  = (const float*)d_in[5];
    const float* Cre  = (const float*)d_in[6];
    const float* Cim  = (const float*)d_in[7];
    const float* Dv   = (const float*)d_in[8];
    float* out = (float*)d_out;
    float* st_re = out + (size_t)B_ * L_ * H_;       // ys first (64 MB)
    float* st_im = st_re + (size_t)B_ * H_ * N2_;    // then imag plane

    // G f16 (12.6 MB) + Lg f32 (131 KB) live in the workspace.
    f16*   G  = (f16*)d_ws;
    float* Lg = (float*)((char*)d_ws + (size_t)H_ * 192 * 64 * 2);

    hipLaunchKernelGGL(k_build, dim3(H_), dim3(256), 0, stream,
                       ldt, Arl, Aim, Bre, Bim, Cre, Cim, Dv, G, Lg);
    hipLaunchKernelGGL(s4d_conv_kernel, dim3(256), dim3(1024), 0, stream,
                       x, G, Lg, out, st_re, st_im);
}

// Round 22
// 204.549 us; speedup vs baseline: 1.3779x; 1.0130x over previous
//
#include <hip/hip_runtime.h>
#include <math.h>

// S4D — round 28: r27 pipeline with the REGISTER BUDGET UNLOCKED.
// r27's spill diagnosis: __launch_bounds__(1024,4) sets only the MIN
// waves/EU; the allocator still targeted 8 waves/SIMD and pinned 64 VGPR,
// spilling the rA/rB prefetch to scratch (FETCH +33 MB, WRITE +58 MB —
// exactly 1024thr x 128B x 512blk each way). Fix: declare the occupancy
// window explicitly with amdgpu_waves_per_eu(4,4) (+flat_work_group_size):
// max 4 waves/EU is already enforced by the 148 KB LDS (1 block/CU), so
// VGPRs up to 512/4 = 128 are free and the prefetch stays in registers.
// Pipeline (unchanged, verified): stage seg0; B1; issue seg1 loads->regs;
// compute seg0 (loads fly); write LDS1; B2; store y0; compute seg1; B3;
// store y1.

#define H_  512
#define L_  4096
#define B_  8
#define N2_ 32
#define SEG 32            // chunks per segment
#define RSTR 72           // tile inner row stride, f16 units (144 B)
#define TSTR 2320         // f16 per tile slot: 32*72 + 16 pad (4640 B)

typedef _Float16 f16;
typedef _Float16 f16x8 __attribute__((ext_vector_type(8)));
typedef _Float16 f16x4 __attribute__((ext_vector_type(4)));
typedef _Float16 f16x2 __attribute__((ext_vector_type(2)));
typedef float    f32x4 __attribute__((ext_vector_type(4)));

__device__ __forceinline__ float bfly1(float v) {   // xor 1: quad_perm [1,0,3,2]
    return __int_as_float(__builtin_amdgcn_update_dpp(
        0, __float_as_int(v), 0xB1, 0xf, 0xf, true));
}

// ---------------- kernel D: per-h matrix build (r22-r27, verified) ---------
// G[h][192][64] f16: T'(+D diag) rows 0..63, M 64..127, V 128..191.
// Lg[h][64] f32: Λ re [0:32), im [32:64).
__global__ __launch_bounds__(256) void k_build(
    const float* __restrict__ log_dt,
    const float* __restrict__ A_real_log,
    const float* __restrict__ A_imag,
    const float* __restrict__ B_re,
    const float* __restrict__ B_im,
    const float* __restrict__ C_re,
    const float* __restrict__ C_im,
    const float* __restrict__ Dv,
    f16*  __restrict__ G,
    float* __restrict__ Lg)
{
    __shared__ float pr[32 * 66], pi[32 * 66];     // dApow [n][66], p=0..64
    __shared__ float s_xr[32], s_xi[32], s_dBr[32], s_dBi[32],
                     s_wr[32], s_wi[32], s_wdr[32], s_wdi[32], s_k[64];
    const int h   = (int)blockIdx.x;
    const int tid = threadIdx.x;

    if (tid < 32) {
        const int n = tid, hn = h * N2_ + n;
        const float dt = expf(log_dt[h]);
        const float Ar = -expf(A_real_log[hn]);
        const float Ai = A_imag[hn];
        const float xr = dt * Ar, xi = dt * Ai;
        s_xr[n] = xr; s_xi[n] = xi;
        const float ex = expf(xr), cs = cosf(xi), sn = sinf(xi);
        const float sh  = sinf(0.5f * xi);
        const float emr = expm1f(xr) * cs - 2.0f * sh * sh;  // Re(expm1(dtA))
        const float emi = ex * sn;
        const float ia  = 1.0f / (Ar * Ar + Ai * Ai);
        const float tr  = (emr * Ar + emi * Ai) * ia;
        const float ti  = (emi * Ar - emr * Ai) * ia;
        const float Brv = B_re[hn], Biv = B_im[hn];
        const float dBr = Brv * tr - Biv * ti, dBi = Brv * ti + Biv * tr;
        s_dBr[n] = dBr; s_dBi[n] = dBi;
        const float wr = 2.0f * C_re[hn], wi = 2.0f * C_im[hn];
        s_wr[n] = wr; s_wi[n] = wi;
        s_wdr[n] = wr * dBr - wi * dBi;             // w*dB
        s_wdi[n] = wr * dBi + wi * dBr;
    }
    __syncthreads();

    for (int e = tid; e < 2048; e += 256) {         // p = 0..63
        const int n = e >> 6, p = e & 63;
        const float ex = expf((float)p * s_xr[n]);
        float sn, cs; sincosf((float)p * s_xi[n], &sn, &cs);
        pr[n * 66 + p] = ex * cs; pi[n * 66 + p] = ex * sn;
    }
    if (tid < 32) {                                 // p = 64
        const int n = tid;
        const float ex = expf(64.f * s_xr[n]);
        float sn, cs; sincosf(64.f * s_xi[n], &sn, &cs);
        pr[n * 66 + 64] = ex * cs; pi[n * 66 + 64] = ex * sn;
    }
    __syncthreads();

    if (tid < 64) {                                 // k[d] = Re(w dB dA^d)
        float acc = 0.f;
        for (int n = 0; n < 32; ++n)
            acc += s_wdr[n] * pr[n * 66 + tid] - s_wdi[n] * pi[n * 66 + tid];
        s_k[tid] = acc;
    }
    if (tid < 32) {                                 // Λ = dA^64
        Lg[h * 64 + tid]      = pr[tid * 66 + 64];
        Lg[h * 64 + 32 + tid] = pi[tid * 66 + 64];
    }
    const float Dh = Dv[h];
    f16* Gh = G + (size_t)h * 192 * 64;
    for (int e = tid; e < 4096; e += 256) {         // M rows 64..127
        const int t = e >> 6, j = e & 63, n = j >> 1;
        const float re = pr[n * 66 + t + 1], im = pi[n * 66 + t + 1];
        const float mv = (j & 1) ? -(s_wr[n] * im + s_wi[n] * re)
                                 :  (s_wr[n] * re - s_wi[n] * im);
        Gh[(size_t)(64 + t) * 64 + j] = (f16)mv;
    }
    for (int e = tid; e < 4096; e += 256) {         // V rows 128..191
        const int r = e >> 6, s = e & 63, n = r >> 1;
        const float re = pr[n * 66 + 63 - s], im = pi[n * 66 + 63 - s];
        const float vv = (r & 1) ? (s_dBr[n] * im + s_dBi[n] * re)
                                 : (s_dBr[n] * re - s_dBi[n] * im);
        Gh[(size_t)(128 + r) * 64 + s] = (f16)vv;
    }
    __syncthreads();                                // s_k ready for all
    for (int e = tid; e < 4096; e += 256) {         // T' rows 0..63 (+D diag)
        const int t = e >> 6, s = e & 63;
        const float tv = (s <= t) ? (s_k[t - s] + (s == t ? Dh : 0.f)) : 0.f;
        Gh[(size_t)t * 64 + s] = (f16)tv;
    }
}

// ---------------- kernel B: pipelined full-line direct-IO convolution ------
__global__
__attribute__((amdgpu_flat_work_group_size(1024, 1024),
               amdgpu_waves_per_eu(4, 4)))
void s4d_conv_kernel(
    const float* __restrict__ x,          // (B, L, H) f32
    const f16*  __restrict__ G,           // (H, 192, 64) f16: T'/M/V
    const float* __restrict__ Lg,         // (H, 64) f32: Λ re|im
    float* __restrict__ y,                // (B, L, H) f32 (gelu'd)
    float* __restrict__ st_re,            // (B, H, N2)
    float* __restrict__ st_im)            // (B, H, N2)
{
    __shared__ f16 XT[2][16 * TSTR];               // 148,480 B: 2 seg-halves

    // XCD swizzle: XCD k owns h-groups [4k,4k+4), all b.
    const int bid = (int)blockIdx.x;               // 0..255
    const int lb  = (bid & 7) * 32 + (bid >> 3);
    const int hg  = lb >> 3;                       // 0..31 (16-h group)
    const int b   = lb & 7;

    const int tid = threadIdx.x;
    const int l   = tid & 63;
    const int w   = tid >> 6;                      // wave -> h = hg*16 + w
    const int h   = hg * 16 + w;
    const int row16 = l & 15, kg = l >> 4;

    const f16* Gh = G + (size_t)h * 192 * 64;

    // ---- Vf preload (global, L2-resident) + Λ ----
    f16x8 Vf[4][2];
#pragma unroll
    for (int mt = 0; mt < 4; ++mt)
#pragma unroll
        for (int ks = 0; ks < 2; ++ks)
            Vf[mt][ks] = *(const f16x8*)
                &Gh[(size_t)(128 + mt * 16 + row16) * 64 + ks * 32 + kg * 8];
    const float lr  = Lg[h * 64 + (l >> 1)];
    const float li0 = Lg[h * 64 + 32 + (l >> 1)];
    const float lis = (l & 1) ? li0 : -li0;

    const int hq = tid & 3;                        // staging: h sub-quad
    const int tp = tid >> 2;                       // t-pair index 0..255
    const float* xb_ = x + (size_t)b * L_ * H_ + hg * 16 + hq * 4;
    float*       yb_ = y + (size_t)b * L_ * H_ + hg * 16 + hq * 4;
    const int physw = (((w & 3) << 2) | (w >> 2)) * TSTR;    // PHYS(w)

    float u = 0.f;                                 // recurrence state (j = l)

    // ================= stage seg0 -> LDS0 =================
#pragma unroll
    for (int iter = 0; iter < 4; ++iter) {
        const int t0 = iter * 512 + tp * 2;
        const f32x4 v0 = *(const f32x4*)&xb_[(size_t)t0 * H_];
        const f32x4 v1 = *(const f32x4*)&xb_[(size_t)(t0 + 1) * H_];
        const int c = (t0 >> 6) & (SEG - 1), s0 = t0 & 63;
#pragma unroll
        for (int j = 0; j < 4; ++j) {
            f16x2 p; p[0] = (f16)v0[j]; p[1] = (f16)v1[j];
            *(f16x2*)&XT[0][((j << 2) | hq) * TSTR + c * RSTR + s0] = p;
        }
    }
    __syncthreads();                               // B1: X0 staged

    // ---- issue seg1 global loads (fly under seg0 compute) ----
    f32x4 rA[4], rB[4];
#pragma unroll
    for (int iter = 0; iter < 4; ++iter) {
        const int t0 = 2048 + iter * 512 + tp * 2;
        rA[iter] = *(const f32x4*)&xb_[(size_t)t0 * H_];
        rB[iter] = *(const f32x4*)&xb_[(size_t)(t0 + 1) * H_];
    }

    // ================= compute macro (one segment) =================
#define COMPUTE_SEG(XHALF)                                                     \
    {                                                                          \
        f16* Xw = &XT[XHALF][physw];                                           \
        f16x8 xbA[2], xbB[2];                                                  \
        _Pragma("unroll")                                                      \
        for (int nt = 0; nt < 2; ++nt) {                                       \
            const int col = nt * 16 + row16;                                   \
            xbA[nt] = *(const f16x8*)&Xw[col * RSTR + kg * 8];                 \
            xbB[nt] = *(const f16x8*)&Xw[col * RSTR + 32 + kg * 8];            \
            f32x4 ac0 = {0.f,0.f,0.f,0.f}, ac1 = {0.f,0.f,0.f,0.f},            \
                  ac2 = {0.f,0.f,0.f,0.f}, ac3 = {0.f,0.f,0.f,0.f};            \
            ac0 = __builtin_amdgcn_mfma_f32_16x16x32_f16(Vf[0][0], xbA[nt], ac0, 0,0,0); \
            ac0 = __builtin_amdgcn_mfma_f32_16x16x32_f16(Vf[0][1], xbB[nt], ac0, 0,0,0); \
            ac1 = __builtin_amdgcn_mfma_f32_16x16x32_f16(Vf[1][0], xbA[nt], ac1, 0,0,0); \
            ac1 = __builtin_amdgcn_mfma_f32_16x16x32_f16(Vf[1][1], xbB[nt], ac1, 0,0,0); \
            ac2 = __builtin_amdgcn_mfma_f32_16x16x32_f16(Vf[2][0], xbA[nt], ac2, 0,0,0); \
            ac2 = __builtin_amdgcn_mfma_f32_16x16x32_f16(Vf[2][1], xbB[nt], ac2, 0,0,0); \
            ac3 = __builtin_amdgcn_mfma_f32_16x16x32_f16(Vf[3][0], xbA[nt], ac3, 0,0,0); \
            ac3 = __builtin_amdgcn_mfma_f32_16x16x32_f16(Vf[3][1], xbB[nt], ac3, 0,0,0); \
            const f32x4 a4[4] = {ac0, ac1, ac2, ac3};                          \
            _Pragma("unroll")                                                  \
            for (int mt = 0; mt < 4; ++mt) {                                   \
                f16x4 pv;                                                      \
                pv[0] = (f16)a4[mt][0]; pv[1] = (f16)a4[mt][1];                \
                pv[2] = (f16)a4[mt][2]; pv[3] = (f16)a4[mt][3];                \
                *(f16x4*)&Xw[col * RSTR + mt * 16 + kg * 4] = pv;              \
            }                                                                  \
        }                                                                      \
        {   /* P6: diagonal recurrence over this segment's 32 chunks */        \
            const int j = l;                                                   \
            for (int c0 = 0; c0 < SEG; c0 += 8) {                              \
                float pv[8];                                                   \
                _Pragma("unroll")                                              \
                for (int k2 = 0; k2 < 8; ++k2)                                 \
                    pv[k2] = (float)Xw[(c0 + k2) * RSTR + j];                  \
                _Pragma("unroll")                                              \
                for (int k2 = 0; k2 < 8; ++k2) {                               \
                    Xw[(c0 + k2) * RSTR + j] = (f16)u;                         \
                    const float usw = bfly1(u);                                \
                    u = fmaf(lr, u, fmaf(lis, usw, pv[k2]));                   \
                }                                                              \
            }                                                                  \
        }                                                                      \
        {   /* P7: Y = T'@X + M@U, gelu -> tile (Tf/Mf streamed) */            \
            f16x8 ub0[2], ub1[2];                                              \
            _Pragma("unroll")                                                  \
            for (int nt = 0; nt < 2; ++nt) {                                   \
                const int col = nt * 16 + row16;                               \
                ub0[nt] = *(const f16x8*)&Xw[col * RSTR + kg * 8];             \
                ub1[nt] = *(const f16x8*)&Xw[col * RSTR + 32 + kg * 8];        \
            }                                                                  \
            _Pragma("unroll")                                                  \
            for (int mt = 0; mt < 4; ++mt) {                                   \
                const size_t rT = (size_t)(mt * 16 + row16) * 64;              \
                const size_t rM = (size_t)(64 + mt * 16 + row16) * 64;         \
                const f16x8 Tf0 = *(const f16x8*)&Gh[rT + kg * 8];             \
                const f16x8 Tf1 = *(const f16x8*)&Gh[rT + 32 + kg * 8];        \
                const f16x8 Mf0 = *(const f16x8*)&Gh[rM + kg * 8];             \
                const f16x8 Mf1 = *(const f16x8*)&Gh[rM + 32 + kg * 8];        \
                _Pragma("unroll")                                              \
                for (int nt = 0; nt < 2; ++nt) {                               \
                    const int col = nt * 16 + row16;                           \
                    f32x4 ac = {0.f, 0.f, 0.f, 0.f};                           \
                    ac = __builtin_amdgcn_mfma_f32_16x16x32_f16(Tf0, xbA[nt], ac, 0,0,0); \
                    ac = __builtin_amdgcn_mfma_f32_16x16x32_f16(Tf1, xbB[nt], ac, 0,0,0); \
                    ac = __builtin_amdgcn_mfma_f32_16x16x32_f16(Mf0, ub0[nt], ac, 0,0,0); \
                    ac = __builtin_amdgcn_mfma_f32_16x16x32_f16(Mf1, ub1[nt], ac, 0,0,0); \
                    const int t0 = mt * 16 + kg * 4;                           \
                    f16x4 pk;                                                  \
                    _Pragma("unroll")                                          \
                    for (int r = 0; r < 4; ++r) {                              \
                        const float yv = ac[r];                                \
                        const float y2 = yv * yv;                              \
                        const float arg = yv * fmaf(-0.10294502f, y2, -2.30218425f); \
                        const float e   = __builtin_amdgcn_exp2f(arg);         \
                        pk[r] = (f16)(yv * __builtin_amdgcn_rcpf(1.0f + e));   \
                    }                                                          \
                    *(f16x4*)&Xw[col * RSTR + t0] = pk;                        \
                }                                                              \
            }                                                                  \
        }                                                                      \
    }

#define STORE_SEG(XHALF, TBASE)                                                \
    {                                                                          \
        _Pragma("unroll")                                                      \
        for (int iter = 0; iter < 4; ++iter) {                                 \
            const int t0 = (TBASE) + iter * 512 + tp * 2;                      \
            const int c = (t0 >> 6) & (SEG - 1), s0 = t0 & 63;                 \
            f32x4 v0, v1;                                                      \
            _Pragma("unroll")                                                  \
            for (int j = 0; j < 4; ++j) {                                      \
                const f16x2 p = *(const f16x2*)                                \
                    &XT[XHALF][((j << 2) | hq) * TSTR + c * RSTR + s0];        \
                v0[j] = (float)p[0]; v1[j] = (float)p[1];                      \
            }                                                                  \
            *(f32x4*)&yb_[(size_t)t0 * H_]       = v0;                         \
            *(f32x4*)&yb_[(size_t)(t0 + 1) * H_] = v1;                         \
        }                                                                      \
    }

    // ================= pipeline =================
    COMPUTE_SEG(0)                                 // y0 into LDS0 (loads fly)

    // write seg1 -> LDS1 (waits only the rA/rB loads)
#pragma unroll
    for (int iter = 0; iter < 4; ++iter) {
        const int t0 = 2048 + iter * 512 + tp * 2;
        const int c = (t0 >> 6) & (SEG - 1), s0 = t0 & 63;
#pragma unroll
        for (int j = 0; j < 4; ++j) {
            f16x2 p; p[0] = (f16)rA[iter][j]; p[1] = (f16)rB[iter][j];
            *(f16x2*)&XT[1][((j << 2) | hq) * TSTR + c * RSTR + s0] = p;
        }
    }
    __syncthreads();                               // B2: y0 done + X1 staged

    STORE_SEG(0, 0)                                // fire-and-forget
    COMPUTE_SEG(1)                                 // y1 into LDS1
    __syncthreads();                               // B3: y1 done in tiles
    STORE_SEG(1, 2048)

    // ---- final state ----
    {
        const int j = l, n = j >> 1;
        const int pairIdx = b * H_ + h;
        if ((j & 1) == 0) st_re[(size_t)pairIdx * N2_ + n] = u;
        else              st_im[(size_t)pairIdx * N2_ + n] = u;
    }
#undef COMPUTE_SEG
#undef STORE_SEG
}

extern "C" void kernel_launch(void* const* d_in, const int* in_sizes, int n_in,
                              void* d_out, int out_size, void* d_ws, size_t ws_size,
                              hipStream_t stream) {
    (void)in_sizes; (void)n_in; (void)out_size; (void)ws_size;
    const float* x    = (const float*)d_in[0];
    const float* ldt  = (const float*)d_in[1];
    const float* Arl  = (const float*)d_in[2];
    const float* Aim  = (const float*)d_in[3];
    const float* Bre  = (const float*)d_in[4];
    const float* Bim  = (const float*)d_in[5];
    const float* Cre  = (const float*)d_in[6];
    const float* Cim  = (const float*)d_in[7];
    const float* Dv   = (const float*)d_in[8];
    float* out = (float*)d_out;
    float* st_re = out + (size_t)B_ * L_ * H_;       // ys first (64 MB)
    float* st_im = st_re + (size_t)B_ * H_ * N2_;    // then imag plane

    // G f16 (12.6 MB) + Lg f32 (131 KB) live in the workspace.
    f16*   G  = (f16*)d_ws;
    float* Lg = (float*)((char*)d_ws + (size_t)H_ * 192 * 64 * 2);

    hipLaunchKernelGGL(k_build, dim3(H_), dim3(256), 0, stream,
                       ldt, Arl, Aim, Bre, Bim, Cre, Cim, Dv, G, Lg);
    hipLaunchKernelGGL(s4d_conv_kernel, dim3(256), dim3(1024), 0, stream,
                       x, G, Lg, out, st_re, st_im);
}